// Round 15
// baseline (394.131 us; speedup 1.0000x reference)
//
#include <hip/hip_runtime.h>

#define HID 512
#define OUTD 7
#define EPSV 1e-5f
#define PB 256    // ln_pool blocks (partial buffer rows)
#define PR 32     // pool_reduce output rows

typedef __attribute__((ext_vector_type(8))) short bf16x8;
typedef __attribute__((ext_vector_type(4))) float f32x4;
typedef __attribute__((ext_vector_type(2))) float f32x2;
typedef unsigned short ushort_t;
typedef unsigned int uint_t;
typedef unsigned char uchar_t;

// ---------------- bf16 helpers ----------------
__device__ __forceinline__ ushort_t f2bf(float f) {
    uint_t u = __float_as_uint(f);
    u = (u + 0x7fffu + ((u >> 16) & 1u)) >> 16;    // RNE
    return (ushort_t)u;
}
__device__ __forceinline__ float bflo(uint_t u) { return __uint_as_float(u << 16); }
__device__ __forceinline__ float bfhi(uint_t u) { return __uint_as_float(u & 0xffff0000u); }

// ---------------- fp8 e4m3 (OCP) helpers — HW cvt ----------------
__device__ __forceinline__ void dec4(uint_t v, float* f) {
    f32x2 p0 = __builtin_amdgcn_cvt_pk_f32_fp8(v, false);
    f32x2 p1 = __builtin_amdgcn_cvt_pk_f32_fp8(v, true);
    f[0] = p0.x; f[1] = p0.y; f[2] = p1.x; f[3] = p1.y;
}
__device__ __forceinline__ uint_t enc4(float a, float b, float c, float d) {
    uint_t r = __builtin_amdgcn_cvt_pk_fp8_f32(a, b, 0, false);
    r = __builtin_amdgcn_cvt_pk_fp8_f32(c, d, r, true);
    return r;
}

// async global->LDS, 16B per lane; LDS dest is wave-uniform base + lane*16
__device__ __forceinline__ void gload_lds16(const ushort_t* g, ushort_t* l) {
    __builtin_amdgcn_global_load_lds(
        (const __attribute__((address_space(1))) uint_t*)g,
        (__attribute__((address_space(3))) uint_t*)l, 16, 0, 0);
}
__device__ __forceinline__ void gload_lds16_u8(const uchar_t* g, uchar_t* l) {
    __builtin_amdgcn_global_load_lds(
        (const __attribute__((address_space(1))) uint_t*)g,
        (__attribute__((address_space(3))) uint_t*)l, 16, 0, 0);
}

// ---------------- setup ----------------

__global__ void deg_count(const int* __restrict__ dst, int* __restrict__ deg, int E) {
    int e = blockIdx.x * blockDim.x + threadIdx.x;
    if (e < E) atomicAdd(&deg[dst[e]], 1);
}

// tiled transpose: W[K][512] fp32 -> Wt[512][K] bf16.  32x32 LDS tiles,
// coalesced float4 reads AND coalesced 8B writes (vs per-element stride-K scatter).
// Weights stay bf16: fp8 weight quant is common-mode across nodes (R11).
__global__ __launch_bounds__(256) void wtrans(
        const float* __restrict__ W0, const float* __restrict__ W1,
        const float* __restrict__ W2, const float* __restrict__ W3,
        ushort_t* __restrict__ T0, ushort_t* __restrict__ T1,
        ushort_t* __restrict__ T2, ushort_t* __restrict__ T3) {
    __shared__ ushort_t tile[32][33];
    int id = blockIdx.x;
    const float* W; ushort_t* T; int K;
    if (id < 64)       { W = W0; T = T0; K = 128; }
    else if (id < 320) { W = W1; T = T1; K = 512; id -= 64; }
    else if (id < 576) { W = W2; T = T2; K = 512; id -= 320; }
    else               { W = W3; T = T3; K = 512; id -= 576; }
    const int tn = id & 15;        // n-tile (512/32)
    const int tk = id >> 4;        // k-tile
    const int t = threadIdx.x;
    const int r = t >> 3;          // 0..31
    const int c4 = (t & 7) * 4;    // 0,4,..,28
    const float4 v = *(const float4*)&W[(size_t)(tk * 32 + r) * HID + tn * 32 + c4];
    tile[r][c4 + 0] = f2bf(v.x); tile[r][c4 + 1] = f2bf(v.y);
    tile[r][c4 + 2] = f2bf(v.z); tile[r][c4 + 3] = f2bf(v.w);
    __syncthreads();
    ushort4 ov = make_ushort4(tile[c4 + 0][r], tile[c4 + 1][r],
                              tile[c4 + 2][r], tile[c4 + 3][r]);
    *(ushort4*)&T[(size_t)(tn * 32 + r) * K + tk * 32 + c4] = ov;
}

// ---------------- hierarchical scan (2 phases) ----------------

__global__ void scan1(const int* __restrict__ deg, int* __restrict__ off,
                      int* __restrict__ partial, float* __restrict__ dinv, int N) {
    __shared__ int s[256];
    const int t = threadIdx.x;
    const int i = blockIdx.x * 256 + t;
    int d = (i < N) ? deg[i] : 0;
    if (i < N) dinv[i] = rsqrtf((float)(d + 1));   // +1 self loop
    s[t] = d;
    __syncthreads();
#pragma unroll
    for (int ofs = 1; ofs < 256; ofs <<= 1) {
        int v = (t >= ofs) ? s[t - ofs] : 0;
        __syncthreads();
        s[t] += v;
        __syncthreads();
    }
    if (i < N) off[i] = s[t] - d;
    if (t == 255) partial[blockIdx.x] = s[255];
}

__global__ void scan23(int* __restrict__ off, const int* __restrict__ partial,
                       int* __restrict__ cursor, int N, int E, int nb) {
    __shared__ int s[256];
    __shared__ int ex[256];
    const int t = threadIdx.x;
    int d = (t < nb) ? partial[t] : 0;
    s[t] = d;
    __syncthreads();
#pragma unroll
    for (int ofs = 1; ofs < 256; ofs <<= 1) {
        int v = (t >= ofs) ? s[t - ofs] : 0;
        __syncthreads();
        s[t] += v;
        __syncthreads();
    }
    ex[t] = s[t] - d;
    __syncthreads();
    int i = blockIdx.x * 256 + t;
    if (i < N) {
        int v = off[i] + ex[i >> 8];
        off[i] = v;
        cursor[i] = v;
    } else if (i == N) {
        off[N] = E;
    }
}

// ---------------- fused: CSR fill + x -> fp8*dinv ----------------

__global__ void fill_cvt(const int* __restrict__ src, const int* __restrict__ dst,
                         int* __restrict__ cursor, int* __restrict__ srcs, int E,
                         const float* __restrict__ x, const float* __restrict__ dinv,
                         ushort_t* __restrict__ xb, int pairs) {
    int i = blockIdx.x * blockDim.x + threadIdx.x;
    if (i < E) { int p = atomicAdd(&cursor[dst[i]], 1); srcs[p] = src[i]; return; }
    i -= E;
    if (i < pairs) {
        float dr = dinv[i >> 6];                      // row = 2i/128
        float a = x[2 * i] * dr, b = x[2 * i + 1] * dr;
        uint_t d = __builtin_amdgcn_cvt_pk_fp8_f32(a, b, 0, false);
        xb[i] = (ushort_t)(d & 0xffffu);
    }
}

// ---------------- aggregation: fp8 gather, multi-edge wave-instructions ----------------
// Input xs is fp8, PRE-SCALED by dinv. ax[r] = fp8( dinv[r] * (xs[r] + sum xs[nbr]) ).
// K=512: 16 B/lane, 32 lanes/row => 2 edges per gather instruction; 8 loads in flight.

__global__ __launch_bounds__(256) void csr_agg_512(
        const uchar_t* __restrict__ xs, const int* __restrict__ off,
        const int* __restrict__ srcs, const float* __restrict__ dinv,
        uchar_t* __restrict__ ax, int N) {
    int gtid = blockIdx.x * 256 + threadIdx.x;
    int r = gtid >> 6, lane = gtid & 63;
    if (r >= N) return;
    const int half = lane >> 5, l32 = lane & 31;
    const uint4* xb = (const uint4*)xs;    // row stride = 32 uint4 (512 B)
    float a[16];
    if (half == 0) {
        uint4 v = xb[(size_t)r * 32 + l32];
        dec4(v.x, a); dec4(v.y, a + 4); dec4(v.z, a + 8); dec4(v.w, a + 12);
    } else {
#pragma unroll
        for (int q = 0; q < 16; q++) a[q] = 0.f;
    }
    int e = off[r];
    const int e1 = off[r + 1];
    // 16 edges per iter: 8 independent uint4 gathers in flight
    for (; e + 16 <= e1; e += 16) {
        int si[8]; uint4 vi[8];
#pragma unroll
        for (int j = 0; j < 8; j++) si[j] = srcs[e + 2 * j + half];
#pragma unroll
        for (int j = 0; j < 8; j++) vi[j] = xb[(size_t)si[j] * 32 + l32];
#pragma unroll
        for (int j = 0; j < 8; j++) {
            float f[16];
            dec4(vi[j].x, f); dec4(vi[j].y, f + 4); dec4(vi[j].z, f + 8); dec4(vi[j].w, f + 12);
#pragma unroll
            for (int q = 0; q < 16; q++) a[q] += f[q];
        }
    }
    for (; e + 8 <= e1; e += 8) {
        int si[4]; uint4 vi[4];
#pragma unroll
        for (int j = 0; j < 4; j++) si[j] = srcs[e + 2 * j + half];
#pragma unroll
        for (int j = 0; j < 4; j++) vi[j] = xb[(size_t)si[j] * 32 + l32];
#pragma unroll
        for (int j = 0; j < 4; j++) {
            float f[16];
            dec4(vi[j].x, f); dec4(vi[j].y, f + 4); dec4(vi[j].z, f + 8); dec4(vi[j].w, f + 12);
#pragma unroll
            for (int q = 0; q < 16; q++) a[q] += f[q];
        }
    }
    for (; e < e1; e += 2) {
        int idx = e + half;
        bool valid = idx < e1;
        int s = srcs[valid ? idx : e];
        uint4 v = xb[(size_t)s * 32 + l32];
        if (!valid) { v.x = 0; v.y = 0; v.z = 0; v.w = 0; }
        float f[16];
        dec4(v.x, f); dec4(v.y, f + 4); dec4(v.z, f + 8); dec4(v.w, f + 12);
#pragma unroll
        for (int q = 0; q < 16; q++) a[q] += f[q];
    }
#pragma unroll
    for (int q = 0; q < 16; q++) a[q] += __shfl_xor(a[q], 32);
    if (half == 0) {
        float dr = dinv[r];
        uint4 o;
        o.x = enc4(a[0] * dr,  a[1] * dr,  a[2] * dr,  a[3] * dr);
        o.y = enc4(a[4] * dr,  a[5] * dr,  a[6] * dr,  a[7] * dr);
        o.z = enc4(a[8] * dr,  a[9] * dr,  a[10] * dr, a[11] * dr);
        o.w = enc4(a[12] * dr, a[13] * dr, a[14] * dr, a[15] * dr);
        ((uint4*)ax)[(size_t)r * 32 + l32] = o;
    }
}

// K=128: 16 B/lane, 8 lanes/row => 8 edges per gather instruction; 2 loads in flight.
__global__ __launch_bounds__(256) void csr_agg_128(
        const uchar_t* __restrict__ xs, const int* __restrict__ off,
        const int* __restrict__ srcs, const float* __restrict__ dinv,
        uchar_t* __restrict__ ax, int N) {
    int gtid = blockIdx.x * 256 + threadIdx.x;
    int r = gtid >> 6, lane = gtid & 63;
    if (r >= N) return;
    const int sub = lane >> 3, l8 = lane & 7;   // 8 edge slots x 8 col-chunks (16B)
    const uint4* xb = (const uint4*)xs;         // row stride = 8 uint4 (128 B)
    float a[16];
    if (sub == 0) {
        uint4 v = xb[(size_t)r * 8 + l8];
        dec4(v.x, a); dec4(v.y, a + 4); dec4(v.z, a + 8); dec4(v.w, a + 12);
    } else {
#pragma unroll
        for (int q = 0; q < 16; q++) a[q] = 0.f;
    }
    int e = off[r];
    const int e1 = off[r + 1];
    for (; e + 16 <= e1; e += 16) {
        int s0 = srcs[e + sub], s1 = srcs[e + 8 + sub];
        uint4 v0 = xb[(size_t)s0 * 8 + l8];
        uint4 v1 = xb[(size_t)s1 * 8 + l8];
        float f[16];
        dec4(v0.x, f); dec4(v0.y, f + 4); dec4(v0.z, f + 8); dec4(v0.w, f + 12);
#pragma unroll
        for (int q = 0; q < 16; q++) a[q] += f[q];
        dec4(v1.x, f); dec4(v1.y, f + 4); dec4(v1.z, f + 8); dec4(v1.w, f + 12);
#pragma unroll
        for (int q = 0; q < 16; q++) a[q] += f[q];
    }
    for (; e < e1; e += 8) {
        int idx = e + sub;
        bool valid = idx < e1;
        int s = srcs[valid ? idx : e];
        uint4 v = xb[(size_t)s * 8 + l8];
        if (!valid) { v.x = 0; v.y = 0; v.z = 0; v.w = 0; }
        float f[16];
        dec4(v.x, f); dec4(v.y, f + 4); dec4(v.z, f + 8); dec4(v.w, f + 12);
#pragma unroll
        for (int q = 0; q < 16; q++) a[q] += f[q];
    }
#pragma unroll
    for (int q = 0; q < 16; q++) a[q] += __shfl_xor(a[q], 8);
#pragma unroll
    for (int q = 0; q < 16; q++) a[q] += __shfl_xor(a[q], 16);
#pragma unroll
    for (int q = 0; q < 16; q++) a[q] += __shfl_xor(a[q], 32);
    if (sub == 0) {
        float dr = dinv[r];
        uint4 o;
        o.x = enc4(a[0] * dr,  a[1] * dr,  a[2] * dr,  a[3] * dr);
        o.y = enc4(a[4] * dr,  a[5] * dr,  a[6] * dr,  a[7] * dr);
        o.z = enc4(a[8] * dr,  a[9] * dr,  a[10] * dr, a[11] * dr);
        o.w = enc4(a[12] * dr, a[13] * dr, a[14] * dr, a[15] * dr);
        ((uint4*)ax)[(size_t)r * 8 + l8] = o;
    }
}

// ---------------- MFMA GEMM: C = A(fp8)[M x K] @ Wt(bf16)[512 x K]^T + bias, bf16 out ----
// 128x128 tile, BK=64, 4 waves (64x64 each, 4x4 frags of 16x16x32 bf16).
// A staged fp8, HW-cvt to bf16 fragments after ds_read. XCD swizzle: the 4 n-blocks
// sharing an m-tile map to the same XCD (id%8) so A-tile re-reads hit that XCD's L2.

__global__ __launch_bounds__(256) void gemm_mfma(
        const uchar_t* __restrict__ A, const ushort_t* __restrict__ Wt,
        const float* __restrict__ bias, ushort_t* __restrict__ C, int M, int K, int MB) {
    __shared__ __align__(16) uchar_t  As[4 * 128 * 16];   // 8 KB
    __shared__ __align__(16) ushort_t Bs[8 * 128 * 8];    // 16 KB
    const int id = blockIdx.x;
    const int mb = (id >> 5) * 8 + (id & 7);
    const int nbk = (id >> 3) & 3;
    if (mb >= MB) return;
    const int t = threadIdx.x;
    const int wave = t >> 6, lane = t & 63;
    const int m0 = mb * 128, n0 = nbk * 128;
    const int wm = (wave & 1) * 64, wn = (wave >> 1) * 64;
    const int quad = lane >> 4, l16 = lane & 15;

    f32x4 acc[4][4];
#pragma unroll
    for (int i = 0; i < 4; i++)
#pragma unroll
        for (int j = 0; j < 4; j++) acc[i][j] = (f32x4){0.f, 0.f, 0.f, 0.f};

    for (int k0 = 0; k0 < K; k0 += 64) {
#pragma unroll
        for (int h = 0; h < 2; h++) {
            int gm = m0 + 64 * h + lane;
            if (gm >= M) gm = M - 1;
            gload_lds16_u8(A + (size_t)gm * K + k0 + wave * 16,
                           &As[(wave * 128 + 64 * h) * 16]);
        }
#pragma unroll
        for (int h = 0; h < 4; h++) {
            int cb = wave * 2 + (h >> 1);
            int row = (h & 1) * 64 + lane;
            gload_lds16(Wt + (size_t)(n0 + row) * K + k0 + cb * 8,
                        &Bs[(cb * 128 + (h & 1) * 64) * 8]);
        }
        __syncthreads();
#pragma unroll
        for (int kk = 0; kk < 2; kk++) {
            bf16x8 af[4], bfr[4];
#pragma unroll
            for (int jn = 0; jn < 4; jn++)
                bfr[jn] = *(const bf16x8*)&Bs[((kk * 4 + quad) * 128 + wn + jn * 16 + l16) * 8];
#pragma unroll
            for (int i = 0; i < 4; i++) {
                uint2 v8 = *(const uint2*)&As[((kk * 2 + (quad >> 1)) * 128 + wm + i * 16 + l16) * 16
                                              + (quad & 1) * 8];
                f32x2 p0 = __builtin_amdgcn_cvt_pk_f32_fp8(v8.x, false);
                f32x2 p1 = __builtin_amdgcn_cvt_pk_f32_fp8(v8.x, true);
                f32x2 p2 = __builtin_amdgcn_cvt_pk_f32_fp8(v8.y, false);
                f32x2 p3 = __builtin_amdgcn_cvt_pk_f32_fp8(v8.y, true);
                union { uint_t u[4]; bf16x8 v; } pk;
                pk.u[0] = (__float_as_uint(p0.y) & 0xffff0000u) | (__float_as_uint(p0.x) >> 16);
                pk.u[1] = (__float_as_uint(p1.y) & 0xffff0000u) | (__float_as_uint(p1.x) >> 16);
                pk.u[2] = (__float_as_uint(p2.y) & 0xffff0000u) | (__float_as_uint(p2.x) >> 16);
                pk.u[3] = (__float_as_uint(p3.y) & 0xffff0000u) | (__float_as_uint(p3.x) >> 16);
                af[i] = pk.v;
            }
#pragma unroll
            for (int i = 0; i < 4; i++)
#pragma unroll
                for (int jn = 0; jn < 4; jn++)
                    acc[i][jn] = __builtin_amdgcn_mfma_f32_16x16x32_bf16(
                                     af[i], bfr[jn], acc[i][jn], 0, 0, 0);
        }
        __syncthreads();
    }
    // epilogue: + bias, pack bf16. D: col = lane&15, row = quad*4 + reg
#pragma unroll
    for (int i = 0; i < 4; i++) {
#pragma unroll
        for (int jn = 0; jn < 4; jn++) {
            int gn = n0 + wn + jn * 16 + l16;
            float bv = bias[gn];
#pragma unroll
            for (int rg = 0; rg < 4; rg++) {
                int gm = m0 + wm + i * 16 + quad * 4 + rg;
                if (gm < M) C[(size_t)gm * HID + gn] = f2bf(acc[i][jn][rg] + bv);
            }
        }
    }
}

// ---------------- LayerNorm + ReLU -> fp8 out, pre-scaled by dinv (layers 0-2) ----------------

__global__ void ln_relu(const ushort_t* __restrict__ h, const float* __restrict__ gamma,
                        const float* __restrict__ beta, const float* __restrict__ dinv,
                        void* __restrict__ optr, int N) {
    int gtid = blockIdx.x * blockDim.x + threadIdx.x;
    int r = gtid >> 6, lane = gtid & 63;
    if (r >= N) return;
    uint4 v = ((const uint4*)(h + (size_t)r * HID))[lane];
    float f[8] = {bflo(v.x), bfhi(v.x), bflo(v.y), bfhi(v.y),
                  bflo(v.z), bfhi(v.z), bflo(v.w), bfhi(v.w)};
    float s = 0.f, q = 0.f;
#pragma unroll
    for (int j = 0; j < 8; j++) { s += f[j]; q += f[j] * f[j]; }
#pragma unroll
    for (int ofs = 32; ofs > 0; ofs >>= 1) {
        s += __shfl_xor(s, ofs);
        q += __shfl_xor(q, ofs);
    }
    float mu  = s * (1.0f / HID);
    float var = q * (1.0f / HID) - mu * mu;
    float rs  = rsqrtf(var + EPSV);
    float dr  = dinv[r];
    const float4* gp = (const float4*)gamma;
    const float4* bp = (const float4*)beta;
    float4 g0 = gp[2 * lane], g1 = gp[2 * lane + 1];
    float4 b0 = bp[2 * lane], b1 = bp[2 * lane + 1];
    float gg[8] = {g0.x, g0.y, g0.z, g0.w, g1.x, g1.y, g1.z, g1.w};
    float bb[8] = {b0.x, b0.y, b0.z, b0.w, b1.x, b1.y, b1.z, b1.w};
    float o[8];
#pragma unroll
    for (int j = 0; j < 8; j++)
        o[j] = fmaxf((f[j] - mu) * rs * gg[j] + bb[j], 0.f) * dr;
    uint2 ov;
    ov.x = enc4(o[0], o[1], o[2], o[3]);
    ov.y = enc4(o[4], o[5], o[6], o[7]);
    ((uint2*)optr)[(size_t)r * 64 + lane] = ov;   // fp8 row: 8 B/lane
}

// ---------------- fused layer-3 LN+ReLU + mean pool — NO atomics ----------------

__global__ __launch_bounds__(256) void ln_pool(
        const ushort_t* __restrict__ h, const float* __restrict__ gamma,
        const float* __restrict__ beta, float* __restrict__ pbuf, int N) {
    __shared__ float sred[4][64][8];
    const int t = threadIdx.x;
    const int sub = t >> 6, lane = t & 63;
    const float4* gp = (const float4*)gamma;
    const float4* bp = (const float4*)beta;
    float4 g0 = gp[2 * lane], g1 = gp[2 * lane + 1];
    float4 b0 = bp[2 * lane], b1 = bp[2 * lane + 1];
    float gg[8] = {g0.x, g0.y, g0.z, g0.w, g1.x, g1.y, g1.z, g1.w};
    float bb[8] = {b0.x, b0.y, b0.z, b0.w, b1.x, b1.y, b1.z, b1.w};
    float colacc[8] = {0.f, 0.f, 0.f, 0.f, 0.f, 0.f, 0.f, 0.f};
    const int step = PB * 4;
    for (int r = blockIdx.x * 4 + sub; r < N; r += step) {
        uint4 v = ((const uint4*)(h + (size_t)r * HID))[lane];
        float f[8] = {bflo(v.x), bfhi(v.x), bflo(v.y), bfhi(v.y),
                      bflo(v.z), bfhi(v.z), bflo(v.w), bfhi(v.w)};
        float s = 0.f, q = 0.f;
#pragma unroll
        for (int j = 0; j < 8; j++) { s += f[j]; q += f[j] * f[j]; }
#pragma unroll
        for (int ofs = 32; ofs > 0; ofs >>= 1) {
            s += __shfl_xor(s, ofs);
            q += __shfl_xor(q, ofs);
        }
        float mu  = s * (1.0f / HID);
        float var = q * (1.0f / HID) - mu * mu;
        float rs  = rsqrtf(var + EPSV);
#pragma unroll
        for (int j = 0; j < 8; j++)
            colacc[j] += fmaxf((f[j] - mu) * rs * gg[j] + bb[j], 0.f);
    }
#pragma unroll
    for (int j = 0; j < 8; j++) sred[sub][lane][j] = colacc[j];
    __syncthreads();
    if (sub == 0) {
        float4 o0, o1;
        o0.x = sred[0][lane][0] + sred[1][lane][0] + sred[2][lane][0] + sred[3][lane][0];
        o0.y = sred[0][lane][1] + sred[1][lane][1] + sred[2][lane][1] + sred[3][lane][1];
        o0.z = sred[0][lane][2] + sred[1][lane][2] + sred[2][lane][2] + sred[3][lane][2];
        o0.w = sred[0][lane][3] + sred[1][lane][3] + sred[2][lane][3] + sred[3][lane][3];
        o1.x = sred[0][lane][4] + sred[1][lane][4] + sred[2][lane][4] + sred[3][lane][4];
        o1.y = sred[0][lane][5] + sred[1][lane][5] + sred[2][lane][5] + sred[3][lane][5];
        o1.z = sred[0][lane][6] + sred[1][lane][6] + sred[2][lane][6] + sred[3][lane][6];
        o1.w = sred[0][lane][7] + sred[1][lane][7] + sred[2][lane][7] + sred[3][lane][7];
        float* pb = pbuf + (size_t)blockIdx.x * HID + lane * 8;
        ((float4*)pb)[0] = o0;
        ((float4*)pb)[1] = o1;
    }
}

// ---------------- hierarchical pool partial reduction: PB rows -> PR rows ----------------

__global__ __launch_bounds__(256) void pool_reduce(
        const float* __restrict__ pbuf, float* __restrict__ pbuf2) {
    const int t = threadIdx.x;
    const int b = blockIdx.x;
    const int R = PB / PR;   // 8 rows per block
    float2 s = make_float2(0.f, 0.f);
#pragma unroll
    for (int u = 0; u < R; u++) {
        const float2 v = ((const float2*)(pbuf + (size_t)(b * R + u) * HID))[t];
        s.x += v.x; s.y += v.y;
    }
    ((float2*)(pbuf2 + (size_t)b * HID))[t] = s;
}

// ---------------- output head: reduce PR partials + project to 7 outs ----------------

__global__ void out_kernel(const float* __restrict__ pbuf2, const float* __restrict__ Wout,
                           const float* __restrict__ bout, float* __restrict__ out, int N) {
    __shared__ float red[256];
    int t = threadIdx.x;
    float g0 = 0.f, g1 = 0.f;
#pragma unroll
    for (int p = 0; p < PR; p += 8) {
#pragma unroll
        for (int u = 0; u < 8; u++) {
            const float2 v = ((const float2*)(pbuf2 + (size_t)(p + u) * HID))[t];
            g0 += v.x; g1 += v.y;
        }
    }
    float invn = 1.0f / (float)N;
    for (int o = 0; o < OUTD; o++) {
        float pr = g0 * Wout[(2 * t) * OUTD + o] + g1 * Wout[(2 * t + 1) * OUTD + o];
        red[t] = pr;
        __syncthreads();
        for (int sft = 128; sft > 0; sft >>= 1) {
            if (t < sft) red[t] += red[t + sft];
            __syncthreads();
        }
        if (t == 0) out[o] = red[0] * invn + bout[o];
        __syncthreads();
    }
}

// ---------------- launch ----------------

extern "C" void kernel_launch(void* const* d_in, const int* in_sizes, int n_in,
                              void* d_out, int out_size, void* d_ws, size_t ws_size,
                              hipStream_t stream) {
    const float* x  = (const float*)d_in[0];
    const int*   ei = (const int*)d_in[1];
    const int N = in_sizes[0] / 128;
    const int E = in_sizes[1] / 2;
    const int* src = ei;
    const int* dst = ei + E;
    const float* Ws[4] = {(const float*)d_in[2], (const float*)d_in[4],
                          (const float*)d_in[6], (const float*)d_in[8]};
    const float* bs[4] = {(const float*)d_in[3], (const float*)d_in[5],
                          (const float*)d_in[7], (const float*)d_in[9]};
    const float* gamma = (const float*)d_in[10];
    const float* beta  = (const float*)d_in[11];
    const float* Wout  = (const float*)d_in[12];
    const float* bout  = (const float*)d_in[13];
    float* out = (float*)d_out;

    // workspace layout (16B-aligned chunks first)
    char* p = (char*)d_ws;
    uchar_t*  axb = (uchar_t*)p;   p += (size_t)N * HID;                      // agg out fp8 (gemm A)
    ushort_t* hb  = (ushort_t*)p;  p += sizeof(ushort_t) * (size_t)N * HID;   // gemm out bf16
    uchar_t*  ho8 = (uchar_t*)p;   p += (size_t)N * HID;                      // fp8 LN out (agg input)
    uchar_t*  xb8 = ho8;           // alias: fp8 x (N*128B, pre-scaled) until ln(l0) overwrites
    ushort_t* Wt[4];
    Wt[0] = (ushort_t*)p;          p += sizeof(ushort_t) * 128 * HID;
    Wt[1] = (ushort_t*)p;          p += sizeof(ushort_t) * HID * HID;
    Wt[2] = (ushort_t*)p;          p += sizeof(ushort_t) * HID * HID;
    Wt[3] = (ushort_t*)p;          p += sizeof(ushort_t) * HID * HID;
    float* dinv  = (float*)p;      p += sizeof(float) * N;
    float* pbuf  = (float*)p;      p += sizeof(float) * PB * HID;             // 512 KB pool partials
    float* pbuf2 = (float*)p;      p += sizeof(float) * PR * HID;             // 64 KB stage-2
    int* deg    = (int*)p;         p += sizeof(int) * N;
    int* off    = (int*)p;         p += sizeof(int) * (N + 4);
    int* cursor = (int*)p;         p += sizeof(int) * N;
    int* partial= (int*)p;         p += sizeof(int) * 256;
    int* srcs   = (int*)p;         // E ints

    const int nb = (N + 255) / 256;
    const int MB = (N + 127) / 128;                  // gemm m-tiles
    const int gemm_blocks = 32 * ((MB + 7) / 8);     // XCD-swizzled flat grid

    // ---- setup: CSR build + conversions (once) ----
    hipMemsetAsync(deg, 0, sizeof(int) * N, stream);   // memset node: graph-capturable
    deg_count<<<(E + 255) / 256, 256, 0, stream>>>(dst, deg, E);
    wtrans<<<832, 256, 0, stream>>>(Ws[0], Ws[1], Ws[2], Ws[3],
                                    Wt[0], Wt[1], Wt[2], Wt[3]);
    scan1<<<nb, 256, 0, stream>>>(deg, off, partial, dinv, N);
    scan23<<<(N + 256) / 256, 256, 0, stream>>>(off, partial, cursor, N, E, nb);
    {
        int pairs = N * 64;   // N*128/2
        int tot = E + pairs;
        fill_cvt<<<(tot + 255) / 256, 256, 0, stream>>>(src, dst, cursor, srcs, E,
                                                        x, dinv, (ushort_t*)xb8, pairs);
    }

    for (int l = 0; l < 4; l++) {
        const int K = (l == 0) ? 128 : HID;
        if (l == 0)
            csr_agg_128<<<(N * 64 + 255) / 256, 256, 0, stream>>>(xb8, off, srcs, dinv, axb, N);
        else
            csr_agg_512<<<(N * 64 + 255) / 256, 256, 0, stream>>>(ho8, off, srcs, dinv, axb, N);
        gemm_mfma<<<gemm_blocks, 256, 0, stream>>>(axb, Wt[l], bs[l], hb, N, K, MB);
        if (l < 3)
            ln_relu<<<(N * 64 + 255) / 256, 256, 0, stream>>>(hb, gamma, beta, dinv, ho8, N);
        else
            ln_pool<<<PB, 256, 0, stream>>>(hb, gamma, beta, pbuf, N);
    }
    pool_reduce<<<PR, 256, 0, stream>>>(pbuf, pbuf2);
    out_kernel<<<1, 256, 0, stream>>>(pbuf2, Wout, bout, out, N);
}

// Round 16
// 370.698 us; speedup vs baseline: 1.0632x; 1.0632x over previous
//
#include <hip/hip_runtime.h>

#define HID 512
#define OUTD 7
#define EPSV 1e-5f
#define PB 256    // ln_pool blocks (partial buffer rows)
#define PR 32     // pool_reduce output rows

typedef __attribute__((ext_vector_type(8))) short bf16x8;
typedef __attribute__((ext_vector_type(4))) float f32x4;
typedef __attribute__((ext_vector_type(2))) float f32x2;
typedef unsigned short ushort_t;
typedef unsigned int uint_t;
typedef unsigned char uchar_t;

// ---------------- bf16 helpers ----------------
__device__ __forceinline__ ushort_t f2bf(float f) {
    uint_t u = __float_as_uint(f);
    u = (u + 0x7fffu + ((u >> 16) & 1u)) >> 16;    // RNE
    return (ushort_t)u;
}
__device__ __forceinline__ float bflo(uint_t u) { return __uint_as_float(u << 16); }
__device__ __forceinline__ float bfhi(uint_t u) { return __uint_as_float(u & 0xffff0000u); }

// ---------------- fp8 e4m3 (OCP) helpers — HW cvt ----------------
__device__ __forceinline__ void dec4(uint_t v, float* f) {
    f32x2 p0 = __builtin_amdgcn_cvt_pk_f32_fp8(v, false);
    f32x2 p1 = __builtin_amdgcn_cvt_pk_f32_fp8(v, true);
    f[0] = p0.x; f[1] = p0.y; f[2] = p1.x; f[3] = p1.y;
}
__device__ __forceinline__ uint_t enc4(float a, float b, float c, float d) {
    uint_t r = __builtin_amdgcn_cvt_pk_fp8_f32(a, b, 0, false);
    r = __builtin_amdgcn_cvt_pk_fp8_f32(c, d, r, true);
    return r;
}

// async global->LDS, 16B per lane; LDS dest is wave-uniform base + lane*16
__device__ __forceinline__ void gload_lds16(const ushort_t* g, ushort_t* l) {
    __builtin_amdgcn_global_load_lds(
        (const __attribute__((address_space(1))) uint_t*)g,
        (__attribute__((address_space(3))) uint_t*)l, 16, 0, 0);
}
__device__ __forceinline__ void gload_lds16_u8(const uchar_t* g, uchar_t* l) {
    __builtin_amdgcn_global_load_lds(
        (const __attribute__((address_space(1))) uint_t*)g,
        (__attribute__((address_space(3))) uint_t*)l, 16, 0, 0);
}

// ---------------- setup ----------------

__global__ void deg_count(const int* __restrict__ dst, int* __restrict__ deg, int E) {
    int e = blockIdx.x * blockDim.x + threadIdx.x;
    if (e < E) atomicAdd(&deg[dst[e]], 1);
}

// tiled transpose: W[K][512] fp32 -> Wt[512][K] bf16.  32x32 LDS tiles,
// coalesced float4 reads AND coalesced 8B writes.
// Weights stay bf16: fp8 weight quant is common-mode across nodes (R11).
__global__ __launch_bounds__(256) void wtrans(
        const float* __restrict__ W0, const float* __restrict__ W1,
        const float* __restrict__ W2, const float* __restrict__ W3,
        ushort_t* __restrict__ T0, ushort_t* __restrict__ T1,
        ushort_t* __restrict__ T2, ushort_t* __restrict__ T3) {
    __shared__ ushort_t tile[32][33];
    int id = blockIdx.x;
    const float* W; ushort_t* T; int K;
    if (id < 64)       { W = W0; T = T0; K = 128; }
    else if (id < 320) { W = W1; T = T1; K = 512; id -= 64; }
    else if (id < 576) { W = W2; T = T2; K = 512; id -= 320; }
    else               { W = W3; T = T3; K = 512; id -= 576; }
    const int tn = id & 15;        // n-tile (512/32)
    const int tk = id >> 4;        // k-tile
    const int t = threadIdx.x;
    const int r = t >> 3;          // 0..31
    const int c4 = (t & 7) * 4;    // 0,4,..,28
    const float4 v = *(const float4*)&W[(size_t)(tk * 32 + r) * HID + tn * 32 + c4];
    tile[r][c4 + 0] = f2bf(v.x); tile[r][c4 + 1] = f2bf(v.y);
    tile[r][c4 + 2] = f2bf(v.z); tile[r][c4 + 3] = f2bf(v.w);
    __syncthreads();
    ushort4 ov = make_ushort4(tile[c4 + 0][r], tile[c4 + 1][r],
                              tile[c4 + 2][r], tile[c4 + 3][r]);
    *(ushort4*)&T[(size_t)(tn * 32 + r) * K + tk * 32 + c4] = ov;
}

// ---------------- hierarchical scan (2 phases) ----------------

__global__ void scan1(const int* __restrict__ deg, int* __restrict__ off,
                      int* __restrict__ partial, float* __restrict__ dinv, int N) {
    __shared__ int s[256];
    const int t = threadIdx.x;
    const int i = blockIdx.x * 256 + t;
    int d = (i < N) ? deg[i] : 0;
    if (i < N) dinv[i] = rsqrtf((float)(d + 1));   // +1 self loop
    s[t] = d;
    __syncthreads();
#pragma unroll
    for (int ofs = 1; ofs < 256; ofs <<= 1) {
        int v = (t >= ofs) ? s[t - ofs] : 0;
        __syncthreads();
        s[t] += v;
        __syncthreads();
    }
    if (i < N) off[i] = s[t] - d;
    if (t == 255) partial[blockIdx.x] = s[255];
}

__global__ void scan23(int* __restrict__ off, const int* __restrict__ partial,
                       int* __restrict__ cursor, int N, int E, int nb) {
    __shared__ int s[256];
    __shared__ int ex[256];
    const int t = threadIdx.x;
    int d = (t < nb) ? partial[t] : 0;
    s[t] = d;
    __syncthreads();
#pragma unroll
    for (int ofs = 1; ofs < 256; ofs <<= 1) {
        int v = (t >= ofs) ? s[t - ofs] : 0;
        __syncthreads();
        s[t] += v;
        __syncthreads();
    }
    ex[t] = s[t] - d;
    __syncthreads();
    int i = blockIdx.x * 256 + t;
    if (i < N) {
        int v = off[i] + ex[i >> 8];
        off[i] = v;
        cursor[i] = v;
    } else if (i == N) {
        off[N] = E;
    }
}

// ---------------- fused: CSR fill + x -> fp8*dinv ----------------

__global__ void fill_cvt(const int* __restrict__ src, const int* __restrict__ dst,
                         int* __restrict__ cursor, int* __restrict__ srcs, int E,
                         const float* __restrict__ x, const float* __restrict__ dinv,
                         ushort_t* __restrict__ xb, int pairs) {
    int i = blockIdx.x * blockDim.x + threadIdx.x;
    if (i < E) { int p = atomicAdd(&cursor[dst[i]], 1); srcs[p] = src[i]; return; }
    i -= E;
    if (i < pairs) {
        float dr = dinv[i >> 6];                      // row = 2i/128
        float a = x[2 * i] * dr, b = x[2 * i + 1] * dr;
        uint_t d = __builtin_amdgcn_cvt_pk_fp8_f32(a, b, 0, false);
        xb[i] = (ushort_t)(d & 0xffffu);
    }
}

// ---------------- aggregation: fp8 gather, multi-edge wave-instructions ----------------
// R14 version — 4 gathers in flight, lean VGPR. R15's deeper unroll REGRESSED
// (+22 µs): on a request-rate-bound gather, ILP beyond ~4 loads only costs
// registers/occupancy (same lesson as R5).

__global__ __launch_bounds__(256) void csr_agg_512(
        const uchar_t* __restrict__ xs, const int* __restrict__ off,
        const int* __restrict__ srcs, const float* __restrict__ dinv,
        uchar_t* __restrict__ ax, int N) {
    int gtid = blockIdx.x * 256 + threadIdx.x;
    int r = gtid >> 6, lane = gtid & 63;
    if (r >= N) return;
    const int half = lane >> 5, l32 = lane & 31;
    const uint4* xb = (const uint4*)xs;    // row stride = 32 uint4 (512 B)
    float a[16];
    if (half == 0) {
        uint4 v = xb[(size_t)r * 32 + l32];
        dec4(v.x, a); dec4(v.y, a + 4); dec4(v.z, a + 8); dec4(v.w, a + 12);
    } else {
#pragma unroll
        for (int q = 0; q < 16; q++) a[q] = 0.f;
    }
    int e = off[r];
    const int e1 = off[r + 1];
    for (; e + 8 <= e1; e += 8) {
        int si[4]; uint4 vi[4];
#pragma unroll
        for (int j = 0; j < 4; j++) si[j] = srcs[e + 2 * j + half];
#pragma unroll
        for (int j = 0; j < 4; j++) vi[j] = xb[(size_t)si[j] * 32 + l32];
#pragma unroll
        for (int j = 0; j < 4; j++) {
            float f[16];
            dec4(vi[j].x, f); dec4(vi[j].y, f + 4); dec4(vi[j].z, f + 8); dec4(vi[j].w, f + 12);
#pragma unroll
            for (int q = 0; q < 16; q++) a[q] += f[q];
        }
    }
    for (; e < e1; e += 2) {
        int idx = e + half;
        bool valid = idx < e1;
        int s = srcs[valid ? idx : e];
        uint4 v = xb[(size_t)s * 32 + l32];
        if (!valid) { v.x = 0; v.y = 0; v.z = 0; v.w = 0; }
        float f[16];
        dec4(v.x, f); dec4(v.y, f + 4); dec4(v.z, f + 8); dec4(v.w, f + 12);
#pragma unroll
        for (int q = 0; q < 16; q++) a[q] += f[q];
    }
#pragma unroll
    for (int q = 0; q < 16; q++) a[q] += __shfl_xor(a[q], 32);
    if (half == 0) {
        float dr = dinv[r];
        uint4 o;
        o.x = enc4(a[0] * dr,  a[1] * dr,  a[2] * dr,  a[3] * dr);
        o.y = enc4(a[4] * dr,  a[5] * dr,  a[6] * dr,  a[7] * dr);
        o.z = enc4(a[8] * dr,  a[9] * dr,  a[10] * dr, a[11] * dr);
        o.w = enc4(a[12] * dr, a[13] * dr, a[14] * dr, a[15] * dr);
        ((uint4*)ax)[(size_t)r * 32 + l32] = o;
    }
}

__global__ __launch_bounds__(256) void csr_agg_128(
        const uchar_t* __restrict__ xs, const int* __restrict__ off,
        const int* __restrict__ srcs, const float* __restrict__ dinv,
        uchar_t* __restrict__ ax, int N) {
    int gtid = blockIdx.x * 256 + threadIdx.x;
    int r = gtid >> 6, lane = gtid & 63;
    if (r >= N) return;
    const int sub = lane >> 3, l8 = lane & 7;   // 8 edge slots x 8 col-chunks (16B)
    const uint4* xb = (const uint4*)xs;         // row stride = 8 uint4 (128 B)
    float a[16];
    if (sub == 0) {
        uint4 v = xb[(size_t)r * 8 + l8];
        dec4(v.x, a); dec4(v.y, a + 4); dec4(v.z, a + 8); dec4(v.w, a + 12);
    } else {
#pragma unroll
        for (int q = 0; q < 16; q++) a[q] = 0.f;
    }
    const int e1 = off[r + 1];
    for (int e = off[r]; e < e1; e += 8) {
        int idx = e + sub;
        bool valid = idx < e1;
        int s = srcs[valid ? idx : e];
        uint4 v = xb[(size_t)s * 8 + l8];
        if (!valid) { v.x = 0; v.y = 0; v.z = 0; v.w = 0; }
        float f[16];
        dec4(v.x, f); dec4(v.y, f + 4); dec4(v.z, f + 8); dec4(v.w, f + 12);
#pragma unroll
        for (int q = 0; q < 16; q++) a[q] += f[q];
    }
#pragma unroll
    for (int q = 0; q < 16; q++) a[q] += __shfl_xor(a[q], 8);
#pragma unroll
    for (int q = 0; q < 16; q++) a[q] += __shfl_xor(a[q], 16);
#pragma unroll
    for (int q = 0; q < 16; q++) a[q] += __shfl_xor(a[q], 32);
    if (sub == 0) {
        float dr = dinv[r];
        uint4 o;
        o.x = enc4(a[0] * dr,  a[1] * dr,  a[2] * dr,  a[3] * dr);
        o.y = enc4(a[4] * dr,  a[5] * dr,  a[6] * dr,  a[7] * dr);
        o.z = enc4(a[8] * dr,  a[9] * dr,  a[10] * dr, a[11] * dr);
        o.w = enc4(a[12] * dr, a[13] * dr, a[14] * dr, a[15] * dr);
        ((uint4*)ax)[(size_t)r * 8 + l8] = o;
    }
}

// ---------------- MFMA GEMM: C = A(fp8)[M x K] @ Wt(bf16)[512 x K]^T + bias, bf16 out ----
// 128x128 tile, BK=64, 4 waves (64x64 each, 4x4 frags of 16x16x32 bf16).
// A staged fp8, HW-cvt to bf16 fragments after ds_read. XCD swizzle: the 4 n-blocks
// sharing an m-tile map to the same XCD (id%8) so A-tile re-reads hit that XCD's L2.

__global__ __launch_bounds__(256) void gemm_mfma(
        const uchar_t* __restrict__ A, const ushort_t* __restrict__ Wt,
        const float* __restrict__ bias, ushort_t* __restrict__ C, int M, int K, int MB) {
    __shared__ __align__(16) uchar_t  As[4 * 128 * 16];   // 8 KB
    __shared__ __align__(16) ushort_t Bs[8 * 128 * 8];    // 16 KB
    const int id = blockIdx.x;
    const int mb = (id >> 5) * 8 + (id & 7);
    const int nbk = (id >> 3) & 3;
    if (mb >= MB) return;
    const int t = threadIdx.x;
    const int wave = t >> 6, lane = t & 63;
    const int m0 = mb * 128, n0 = nbk * 128;
    const int wm = (wave & 1) * 64, wn = (wave >> 1) * 64;
    const int quad = lane >> 4, l16 = lane & 15;

    f32x4 acc[4][4];
#pragma unroll
    for (int i = 0; i < 4; i++)
#pragma unroll
        for (int j = 0; j < 4; j++) acc[i][j] = (f32x4){0.f, 0.f, 0.f, 0.f};

    for (int k0 = 0; k0 < K; k0 += 64) {
#pragma unroll
        for (int h = 0; h < 2; h++) {
            int gm = m0 + 64 * h + lane;
            if (gm >= M) gm = M - 1;
            gload_lds16_u8(A + (size_t)gm * K + k0 + wave * 16,
                           &As[(wave * 128 + 64 * h) * 16]);
        }
#pragma unroll
        for (int h = 0; h < 4; h++) {
            int cb = wave * 2 + (h >> 1);
            int row = (h & 1) * 64 + lane;
            gload_lds16(Wt + (size_t)(n0 + row) * K + k0 + cb * 8,
                        &Bs[(cb * 128 + (h & 1) * 64) * 8]);
        }
        __syncthreads();
#pragma unroll
        for (int kk = 0; kk < 2; kk++) {
            bf16x8 af[4], bfr[4];
#pragma unroll
            for (int jn = 0; jn < 4; jn++)
                bfr[jn] = *(const bf16x8*)&Bs[((kk * 4 + quad) * 128 + wn + jn * 16 + l16) * 8];
#pragma unroll
            for (int i = 0; i < 4; i++) {
                uint2 v8 = *(const uint2*)&As[((kk * 2 + (quad >> 1)) * 128 + wm + i * 16 + l16) * 16
                                              + (quad & 1) * 8];
                f32x2 p0 = __builtin_amdgcn_cvt_pk_f32_fp8(v8.x, false);
                f32x2 p1 = __builtin_amdgcn_cvt_pk_f32_fp8(v8.x, true);
                f32x2 p2 = __builtin_amdgcn_cvt_pk_f32_fp8(v8.y, false);
                f32x2 p3 = __builtin_amdgcn_cvt_pk_f32_fp8(v8.y, true);
                union { uint_t u[4]; bf16x8 v; } pk;
                pk.u[0] = (__float_as_uint(p0.y) & 0xffff0000u) | (__float_as_uint(p0.x) >> 16);
                pk.u[1] = (__float_as_uint(p1.y) & 0xffff0000u) | (__float_as_uint(p1.x) >> 16);
                pk.u[2] = (__float_as_uint(p2.y) & 0xffff0000u) | (__float_as_uint(p2.x) >> 16);
                pk.u[3] = (__float_as_uint(p3.y) & 0xffff0000u) | (__float_as_uint(p3.x) >> 16);
                af[i] = pk.v;
            }
#pragma unroll
            for (int i = 0; i < 4; i++)
#pragma unroll
                for (int jn = 0; jn < 4; jn++)
                    acc[i][jn] = __builtin_amdgcn_mfma_f32_16x16x32_bf16(
                                     af[i], bfr[jn], acc[i][jn], 0, 0, 0);
        }
        __syncthreads();
    }
    // epilogue: + bias, pack bf16. D: col = lane&15, row = quad*4 + reg
#pragma unroll
    for (int i = 0; i < 4; i++) {
#pragma unroll
        for (int jn = 0; jn < 4; jn++) {
            int gn = n0 + wn + jn * 16 + l16;
            float bv = bias[gn];
#pragma unroll
            for (int rg = 0; rg < 4; rg++) {
                int gm = m0 + wm + i * 16 + quad * 4 + rg;
                if (gm < M) C[(size_t)gm * HID + gn] = f2bf(acc[i][jn][rg] + bv);
            }
        }
    }
}

// ---------------- LayerNorm + ReLU -> fp8 out, pre-scaled by dinv (layers 0-2) ----------------

__global__ void ln_relu(const ushort_t* __restrict__ h, const float* __restrict__ gamma,
                        const float* __restrict__ beta, const float* __restrict__ dinv,
                        void* __restrict__ optr, int N) {
    int gtid = blockIdx.x * blockDim.x + threadIdx.x;
    int r = gtid >> 6, lane = gtid & 63;
    if (r >= N) return;
    uint4 v = ((const uint4*)(h + (size_t)r * HID))[lane];
    float f[8] = {bflo(v.x), bfhi(v.x), bflo(v.y), bfhi(v.y),
                  bflo(v.z), bfhi(v.z), bflo(v.w), bfhi(v.w)};
    float s = 0.f, q = 0.f;
#pragma unroll
    for (int j = 0; j < 8; j++) { s += f[j]; q += f[j] * f[j]; }
#pragma unroll
    for (int ofs = 32; ofs > 0; ofs >>= 1) {
        s += __shfl_xor(s, ofs);
        q += __shfl_xor(q, ofs);
    }
    float mu  = s * (1.0f / HID);
    float var = q * (1.0f / HID) - mu * mu;
    float rs  = rsqrtf(var + EPSV);
    float dr  = dinv[r];
    const float4* gp = (const float4*)gamma;
    const float4* bp = (const float4*)beta;
    float4 g0 = gp[2 * lane], g1 = gp[2 * lane + 1];
    float4 b0 = bp[2 * lane], b1 = bp[2 * lane + 1];
    float gg[8] = {g0.x, g0.y, g0.z, g0.w, g1.x, g1.y, g1.z, g1.w};
    float bb[8] = {b0.x, b0.y, b0.z, b0.w, b1.x, b1.y, b1.z, b1.w};
    float o[8];
#pragma unroll
    for (int j = 0; j < 8; j++)
        o[j] = fmaxf((f[j] - mu) * rs * gg[j] + bb[j], 0.f) * dr;
    uint2 ov;
    ov.x = enc4(o[0], o[1], o[2], o[3]);
    ov.y = enc4(o[4], o[5], o[6], o[7]);
    ((uint2*)optr)[(size_t)r * 64 + lane] = ov;   // fp8 row: 8 B/lane
}

// ---------------- fused layer-3 LN+ReLU + mean pool — NO atomics ----------------

__global__ __launch_bounds__(256) void ln_pool(
        const ushort_t* __restrict__ h, const float* __restrict__ gamma,
        const float* __restrict__ beta, float* __restrict__ pbuf, int N) {
    __shared__ float sred[4][64][8];
    const int t = threadIdx.x;
    const int sub = t >> 6, lane = t & 63;
    const float4* gp = (const float4*)gamma;
    const float4* bp = (const float4*)beta;
    float4 g0 = gp[2 * lane], g1 = gp[2 * lane + 1];
    float4 b0 = bp[2 * lane], b1 = bp[2 * lane + 1];
    float gg[8] = {g0.x, g0.y, g0.z, g0.w, g1.x, g1.y, g1.z, g1.w};
    float bb[8] = {b0.x, b0.y, b0.z, b0.w, b1.x, b1.y, b1.z, b1.w};
    float colacc[8] = {0.f, 0.f, 0.f, 0.f, 0.f, 0.f, 0.f, 0.f};
    const int step = PB * 4;
    for (int r = blockIdx.x * 4 + sub; r < N; r += step) {
        uint4 v = ((const uint4*)(h + (size_t)r * HID))[lane];
        float f[8] = {bflo(v.x), bfhi(v.x), bflo(v.y), bfhi(v.y),
                      bflo(v.z), bfhi(v.z), bflo(v.w), bfhi(v.w)};
        float s = 0.f, q = 0.f;
#pragma unroll
        for (int j = 0; j < 8; j++) { s += f[j]; q += f[j] * f[j]; }
#pragma unroll
        for (int ofs = 32; ofs > 0; ofs >>= 1) {
            s += __shfl_xor(s, ofs);
            q += __shfl_xor(q, ofs);
        }
        float mu  = s * (1.0f / HID);
        float var = q * (1.0f / HID) - mu * mu;
        float rs  = rsqrtf(var + EPSV);
#pragma unroll
        for (int j = 0; j < 8; j++)
            colacc[j] += fmaxf((f[j] - mu) * rs * gg[j] + bb[j], 0.f);
    }
#pragma unroll
    for (int j = 0; j < 8; j++) sred[sub][lane][j] = colacc[j];
    __syncthreads();
    if (sub == 0) {
        float4 o0, o1;
        o0.x = sred[0][lane][0] + sred[1][lane][0] + sred[2][lane][0] + sred[3][lane][0];
        o0.y = sred[0][lane][1] + sred[1][lane][1] + sred[2][lane][1] + sred[3][lane][1];
        o0.z = sred[0][lane][2] + sred[1][lane][2] + sred[2][lane][2] + sred[3][lane][2];
        o0.w = sred[0][lane][3] + sred[1][lane][3] + sred[2][lane][3] + sred[3][lane][3];
        o1.x = sred[0][lane][4] + sred[1][lane][4] + sred[2][lane][4] + sred[3][lane][4];
        o1.y = sred[0][lane][5] + sred[1][lane][5] + sred[2][lane][5] + sred[3][lane][5];
        o1.z = sred[0][lane][6] + sred[1][lane][6] + sred[2][lane][6] + sred[3][lane][6];
        o1.w = sred[0][lane][7] + sred[1][lane][7] + sred[2][lane][7] + sred[3][lane][7];
        float* pb = pbuf + (size_t)blockIdx.x * HID + lane * 8;
        ((float4*)pb)[0] = o0;
        ((float4*)pb)[1] = o1;
    }
}

// ---------------- hierarchical pool partial reduction: PB rows -> PR rows ----------------

__global__ __launch_bounds__(256) void pool_reduce(
        const float* __restrict__ pbuf, float* __restrict__ pbuf2) {
    const int t = threadIdx.x;
    const int b = blockIdx.x;
    const int R = PB / PR;   // 8 rows per block
    float2 s = make_float2(0.f, 0.f);
#pragma unroll
    for (int u = 0; u < R; u++) {
        const float2 v = ((const float2*)(pbuf + (size_t)(b * R + u) * HID))[t];
        s.x += v.x; s.y += v.y;
    }
    ((float2*)(pbuf2 + (size_t)b * HID))[t] = s;
}

// ---------------- output head: reduce PR partials + project to 7 outs ----------------

__global__ void out_kernel(const float* __restrict__ pbuf2, const float* __restrict__ Wout,
                           const float* __restrict__ bout, float* __restrict__ out, int N) {
    __shared__ float red[256];
    int t = threadIdx.x;
    float g0 = 0.f, g1 = 0.f;
#pragma unroll
    for (int p = 0; p < PR; p += 8) {
#pragma unroll
        for (int u = 0; u < 8; u++) {
            const float2 v = ((const float2*)(pbuf2 + (size_t)(p + u) * HID))[t];
            g0 += v.x; g1 += v.y;
        }
    }
    float invn = 1.0f / (float)N;
    for (int o = 0; o < OUTD; o++) {
        float pr = g0 * Wout[(2 * t) * OUTD + o] + g1 * Wout[(2 * t + 1) * OUTD + o];
        red[t] = pr;
        __syncthreads();
        for (int sft = 128; sft > 0; sft >>= 1) {
            if (t < sft) red[t] += red[t + sft];
            __syncthreads();
        }
        if (t == 0) out[o] = red[0] * invn + bout[o];
        __syncthreads();
    }
}

// ---------------- launch ----------------

extern "C" void kernel_launch(void* const* d_in, const int* in_sizes, int n_in,
                              void* d_out, int out_size, void* d_ws, size_t ws_size,
                              hipStream_t stream) {
    const float* x  = (const float*)d_in[0];
    const int*   ei = (const int*)d_in[1];
    const int N = in_sizes[0] / 128;
    const int E = in_sizes[1] / 2;
    const int* src = ei;
    const int* dst = ei + E;
    const float* Ws[4] = {(const float*)d_in[2], (const float*)d_in[4],
                          (const float*)d_in[6], (const float*)d_in[8]};
    const float* bs[4] = {(const float*)d_in[3], (const float*)d_in[5],
                          (const float*)d_in[7], (const float*)d_in[9]};
    const float* gamma = (const float*)d_in[10];
    const float* beta  = (const float*)d_in[11];
    const float* Wout  = (const float*)d_in[12];
    const float* bout  = (const float*)d_in[13];
    float* out = (float*)d_out;

    // workspace layout (16B-aligned chunks first)
    char* p = (char*)d_ws;
    uchar_t*  axb = (uchar_t*)p;   p += (size_t)N * HID;                      // agg out fp8 (gemm A)
    ushort_t* hb  = (ushort_t*)p;  p += sizeof(ushort_t) * (size_t)N * HID;   // gemm out bf16
    uchar_t*  ho8 = (uchar_t*)p;   p += (size_t)N * HID;                      // fp8 LN out (agg input)
    uchar_t*  xb8 = ho8;           // alias: fp8 x (N*128B, pre-scaled) until ln(l0) overwrites
    ushort_t* Wt[4];
    Wt[0] = (ushort_t*)p;          p += sizeof(ushort_t) * 128 * HID;
    Wt[1] = (ushort_t*)p;          p += sizeof(ushort_t) * HID * HID;
    Wt[2] = (ushort_t*)p;          p += sizeof(ushort_t) * HID * HID;
    Wt[3] = (ushort_t*)p;          p += sizeof(ushort_t) * HID * HID;
    float* dinv  = (float*)p;      p += sizeof(float) * N;
    float* pbuf  = (float*)p;      p += sizeof(float) * PB * HID;             // 512 KB pool partials
    float* pbuf2 = (float*)p;      p += sizeof(float) * PR * HID;             // 64 KB stage-2
    int* deg    = (int*)p;         p += sizeof(int) * N;
    int* off    = (int*)p;         p += sizeof(int) * (N + 4);
    int* cursor = (int*)p;         p += sizeof(int) * N;
    int* partial= (int*)p;         p += sizeof(int) * 256;
    int* srcs   = (int*)p;         // E ints

    const int nb = (N + 255) / 256;
    const int MB = (N + 127) / 128;                  // gemm m-tiles
    const int gemm_blocks = 32 * ((MB + 7) / 8);     // XCD-swizzled flat grid

    // ---- setup: CSR build + conversions (once) ----
    hipMemsetAsync(deg, 0, sizeof(int) * N, stream);   // memset node: graph-capturable
    deg_count<<<(E + 255) / 256, 256, 0, stream>>>(dst, deg, E);
    wtrans<<<832, 256, 0, stream>>>(Ws[0], Ws[1], Ws[2], Ws[3],
                                    Wt[0], Wt[1], Wt[2], Wt[3]);
    scan1<<<nb, 256, 0, stream>>>(deg, off, partial, dinv, N);
    scan23<<<(N + 256) / 256, 256, 0, stream>>>(off, partial, cursor, N, E, nb);
    {
        int pairs = N * 64;   // N*128/2
        int tot = E + pairs;
        fill_cvt<<<(tot + 255) / 256, 256, 0, stream>>>(src, dst, cursor, srcs, E,
                                                        x, dinv, (ushort_t*)xb8, pairs);
    }

    for (int l = 0; l < 4; l++) {
        const int K = (l == 0) ? 128 : HID;
        if (l == 0)
            csr_agg_128<<<(N * 64 + 255) / 256, 256, 0, stream>>>(xb8, off, srcs, dinv, axb, N);
        else
            csr_agg_512<<<(N * 64 + 255) / 256, 256, 0, stream>>>(ho8, off, srcs, dinv, axb, N);
        gemm_mfma<<<gemm_blocks, 256, 0, stream>>>(axb, Wt[l], bs[l], hb, N, K, MB);
        if (l < 3)
            ln_relu<<<(N * 64 + 255) / 256, 256, 0, stream>>>(hb, gamma, beta, dinv, ho8, N);
        else
            ln_pool<<<PB, 256, 0, stream>>>(hb, gamma, beta, pbuf, N);
    }
    pool_reduce<<<PR, 256, 0, stream>>>(pbuf, pbuf2);
    out_kernel<<<1, 256, 0, stream>>>(pbuf2, Wout, bout, out, N);
}